// Round 2
// baseline (358.577 us; speedup 1.0000x reference)
//
#include <hip/hip_runtime.h>
#include <hip/hip_bf16.h>

#define NN 8192

typedef __attribute__((ext_vector_type(8))) short short8;
typedef __attribute__((ext_vector_type(4))) float f32x4;

static __device__ __forceinline__ float bf2f(unsigned short u) {
    union { unsigned int i; float f; } v; v.i = ((unsigned int)u) << 16; return v.f;
}
static __device__ __forceinline__ unsigned short f2bf(float f) {
    union { float f; unsigned int i; } v; v.f = f;
    unsigned int lsb = (v.i >> 16) & 1u;
    v.i += 0x7fffu + lsb;
    return (unsigned short)(v.i >> 16);
}

// Convert 8 contiguous f32 to bf16 hi + bf16 residual lo (for split-MFMA).
static __device__ __forceinline__ void cvt8(const float* __restrict__ p, short8& hi, short8& lo) {
    float4 u = *(const float4*)p;
    float4 v = *(const float4*)(p + 4);
    float f[8] = {u.x, u.y, u.z, u.w, v.x, v.y, v.z, v.w};
#pragma unroll
    for (int j = 0; j < 8; ++j) {
        unsigned short hb = f2bf(f[j]);
        hi[j] = (short)hb;
        lo[j] = (short)f2bf(f[j] - bf2f(hb));
    }
}

// v1[h][k] = sum_c W1[h*128+c][k] * a1[h][c];  v2 likewise with a2.
// bd[h*2+0] = b1 . a1 (head h), bd[h*2+1] = b2 . a2.
__global__ void prep_kernel(const float* __restrict__ W1, const float* __restrict__ b1,
                            const float* __restrict__ W2, const float* __restrict__ b2,
                            const float* __restrict__ a,
                            float* __restrict__ v1, float* __restrict__ v2, float* __restrict__ bd) {
    int t = threadIdx.x;           // 512 threads: (h, k)
    int hh = t >> 8, k = t & 255;
    float acc1 = 0.f, acc2 = 0.f;
    for (int c = 0; c < 128; ++c) {
        acc1 += W1[(size_t)(hh*128 + c)*256 + k] * a[hh*256 + c];
        acc2 += W2[(size_t)(hh*128 + c)*256 + k] * a[hh*256 + 128 + c];
    }
    v1[hh*256 + k] = acc1;
    v2[hh*256 + k] = acc2;
    if (k == 0) {
        float d1 = 0.f, d2 = 0.f;
        for (int c = 0; c < 128; ++c) {
            d1 += b1[hh*128 + c] * a[hh*256 + c];
            d2 += b2[hh*128 + c] * a[hh*256 + 128 + c];
        }
        bd[hh*2 + 0] = d1;
        bd[hh*2 + 1] = d2;
    }
}

// s1[n][h], s2[n][h] f32, interleaved pairs. One wave per row, fully coalesced.
__global__ __launch_bounds__(256) void s_kernel(const float* __restrict__ hmat,
                         const float* __restrict__ v1, const float* __restrict__ v2,
                         const float* __restrict__ bd,
                         float* __restrict__ s1o, float* __restrict__ s2o) {
    int w = threadIdx.x >> 6, l = threadIdx.x & 63;
    int n = blockIdx.x * 4 + w;
    float4 hv  = *(const float4*)(hmat + (size_t)n * 256 + l * 4);
    float4 va0 = *(const float4*)(v1 + l * 4);
    float4 va1 = *(const float4*)(v1 + 256 + l * 4);
    float4 vb0 = *(const float4*)(v2 + l * 4);
    float4 vb1 = *(const float4*)(v2 + 256 + l * 4);
    float s10 = hv.x*va0.x + hv.y*va0.y + hv.z*va0.z + hv.w*va0.w;
    float s11 = hv.x*va1.x + hv.y*va1.y + hv.z*va1.z + hv.w*va1.w;
    float s20 = hv.x*vb0.x + hv.y*vb0.y + hv.z*vb0.z + hv.w*vb0.w;
    float s21 = hv.x*vb1.x + hv.y*vb1.y + hv.z*vb1.z + hv.w*vb1.w;
#pragma unroll
    for (int off = 1; off < 64; off <<= 1) {
        s10 += __shfl_xor(s10, off);
        s11 += __shfl_xor(s11, off);
        s20 += __shfl_xor(s20, off);
        s21 += __shfl_xor(s21, off);
    }
    if (l == 0) {
        s1o[n*2 + 0] = s10 + bd[0];
        s1o[n*2 + 1] = s11 + bd[2];
        s2o[n*2 + 0] = s20 + bd[1];
        s2o[n*2 + 1] = s21 + bd[3];
    }
}

// W3hT[c][n] = (h @ W3^T + b3)[n][c], bf16, transposed for k-contiguous B-frags later.
// Split-bf16: acc = hi*hi + lo*hi + hi*lo  => ~f32 accuracy before the single bf16 store.
__global__ __launch_bounds__(256) void w3_kernel(const float* __restrict__ hmat,
                                                 const float* __restrict__ W3,
                                                 const float* __restrict__ b3,
                                                 unsigned short* __restrict__ w3t) {
    int tid = threadIdx.x;
    int w = tid >> 6, l = tid & 63;
    int m = l & 15, kq = l >> 4;
    int n0 = blockIdx.x * 64 + w * 16;
    f32x4 acc[16];
#pragma unroll
    for (int ct = 0; ct < 16; ++ct) acc[ct] = (f32x4){0.f, 0.f, 0.f, 0.f};
    for (int k0 = 0; k0 < 256; k0 += 32) {
        short8 ahi, alo;
        cvt8(hmat + (size_t)(n0 + m) * 256 + k0 + kq * 8, ahi, alo);
#pragma unroll
        for (int ct = 0; ct < 16; ++ct) {
            short8 bhi, blo;
            cvt8(W3 + (size_t)(ct * 16 + m) * 256 + k0 + kq * 8, bhi, blo);
            acc[ct] = __builtin_amdgcn_mfma_f32_16x16x32_bf16(ahi, bhi, acc[ct], 0, 0, 0);
            acc[ct] = __builtin_amdgcn_mfma_f32_16x16x32_bf16(alo, bhi, acc[ct], 0, 0, 0);
            acc[ct] = __builtin_amdgcn_mfma_f32_16x16x32_bf16(ahi, blo, acc[ct], 0, 0, 0);
        }
    }
#pragma unroll
    for (int ct = 0; ct < 16; ++ct) {
        int c = ct * 16 + m;
        float bias = b3[c];
#pragma unroll
        for (int r = 0; r < 4; ++r) {
            int nn = n0 + kq * 4 + r;
            w3t[(size_t)c * NN + nn] = f2bf(acc[ct][r] + bias);
        }
    }
}

// Main fused attention: block = 4 waves x 32 rows = 128 rows, full 256 out cols.
// grid = (64 row-blocks, S j-chunks). P generated in A-frag layout, exp without shift
// (scores bounded ~16, exp fits f32/bf16 comfortably; softmax is shift-invariant).
template<int DIRECT>
__global__ __launch_bounds__(256) void attn_kernel(
        const int* __restrict__ adj, const float* __restrict__ s1a,
        const float* __restrict__ s2a, const unsigned short* __restrict__ w3t,
        float* __restrict__ pacc, float* __restrict__ pden,
        float* __restrict__ out, int jc)
{
    int tid = threadIdx.x;
    int w = tid >> 6, l = tid & 63;
    int m = l & 15, kq = l >> 4;
    int i0 = blockIdx.x * 128 + w * 32;
    int sidx = blockIdx.y;
    int ia = i0 + m, ib = i0 + 16 + m;
    float s1a0 = s1a[ia*2 + 0], s1a1 = s1a[ia*2 + 1];
    float s1b0 = s1a[ib*2 + 0], s1b1 = s1a[ib*2 + 1];
    f32x4 acc[2][16];
#pragma unroll
    for (int rt = 0; rt < 2; ++rt)
#pragma unroll
        for (int ct = 0; ct < 16; ++ct) acc[rt][ct] = (f32x4){0.f, 0.f, 0.f, 0.f};
    float dsa0 = 0.f, dsa1 = 0.f, dsb0 = 0.f, dsb1 = 0.f;
    const size_t rowa = (size_t)ia * NN, rowb = (size_t)ib * NN;
    const int jccount = jc;
    for (int jt = 0; jt < jccount; jt += 32) {
        int jb = sidx * jccount + jt + kq * 8;
        int4 A0 = *(const int4*)(adj + rowa + jb);
        int4 A1 = *(const int4*)(adj + rowa + jb + 4);
        int4 B0 = *(const int4*)(adj + rowb + jb);
        int4 B1 = *(const int4*)(adj + rowb + jb + 4);
        int aj[8] = {A0.x, A0.y, A0.z, A0.w, A1.x, A1.y, A1.z, A1.w};
        int bj[8] = {B0.x, B0.y, B0.z, B0.w, B1.x, B1.y, B1.z, B1.w};
        short8 pa0, pa1, pb0, pb1;
#pragma unroll
        for (int jj = 0; jj < 8; ++jj) {
            float2 sv = *(const float2*)(s2a + 2 * (jb + jj));
            float t, p; unsigned short pbits;
            t = s1a0 + sv.x; t = fmaxf(t, 0.2f * t);
            p = aj[jj] ? __expf(t) : 0.f;
            pbits = f2bf(p); pa0[jj] = (short)pbits; dsa0 += bf2f(pbits);
            t = s1a1 + sv.y; t = fmaxf(t, 0.2f * t);
            p = aj[jj] ? __expf(t) : 0.f;
            pbits = f2bf(p); pa1[jj] = (short)pbits; dsa1 += bf2f(pbits);
            t = s1b0 + sv.x; t = fmaxf(t, 0.2f * t);
            p = bj[jj] ? __expf(t) : 0.f;
            pbits = f2bf(p); pb0[jj] = (short)pbits; dsb0 += bf2f(pbits);
            t = s1b1 + sv.y; t = fmaxf(t, 0.2f * t);
            p = bj[jj] ? __expf(t) : 0.f;
            pbits = f2bf(p); pb1[jj] = (short)pbits; dsb1 += bf2f(pbits);
        }
#pragma unroll
        for (int ct = 0; ct < 16; ++ct) {
            short8 bfrag = *(const short8*)(w3t + (size_t)(ct * 16 + m) * NN + jb);
            acc[0][ct] = __builtin_amdgcn_mfma_f32_16x16x32_bf16(ct < 8 ? pa0 : pa1, bfrag, acc[0][ct], 0, 0, 0);
            acc[1][ct] = __builtin_amdgcn_mfma_f32_16x16x32_bf16(ct < 8 ? pb0 : pb1, bfrag, acc[1][ct], 0, 0, 0);
        }
    }
    dsa0 += __shfl_xor(dsa0, 16); dsa0 += __shfl_xor(dsa0, 32);
    dsa1 += __shfl_xor(dsa1, 16); dsa1 += __shfl_xor(dsa1, 32);
    dsb0 += __shfl_xor(dsb0, 16); dsb0 += __shfl_xor(dsb0, 32);
    dsb1 += __shfl_xor(dsb1, 16); dsb1 += __shfl_xor(dsb1, 32);
    if (DIRECT) {
#pragma unroll
        for (int r = 0; r < 4; ++r) {
            int rr = kq * 4 + r;
            float da0 = __shfl(dsa0, rr), da1 = __shfl(dsa1, rr);
            float db0 = __shfl(dsb0, rr), db1 = __shfl(dsb1, rr);
            float ra0 = 1.f/da0, ra1 = 1.f/da1, rb0 = 1.f/db0, rb1 = 1.f/db1;
#pragma unroll
            for (int ct = 0; ct < 16; ++ct) {
                out[(size_t)(i0 + rr)*256 + ct*16 + m]      = acc[0][ct][r] * (ct < 8 ? ra0 : ra1);
                out[(size_t)(i0 + 16 + rr)*256 + ct*16 + m] = acc[1][ct][r] * (ct < 8 ? rb0 : rb1);
            }
        }
    } else {
        if (l < 16) {
            size_t base = (size_t)sidx * NN;
            pden[(base + ia)*2 + 0] = dsa0;
            pden[(base + ia)*2 + 1] = dsa1;
            pden[(base + ib)*2 + 0] = dsb0;
            pden[(base + ib)*2 + 1] = dsb1;
        }
        size_t pb_ = (size_t)sidx * NN * 256;
#pragma unroll
        for (int r = 0; r < 4; ++r) {
            int rr = kq * 4 + r;
#pragma unroll
            for (int ct = 0; ct < 16; ++ct) {
                pacc[pb_ + (size_t)(i0 + rr)*256 + ct*16 + m]      = acc[0][ct][r];
                pacc[pb_ + (size_t)(i0 + 16 + rr)*256 + ct*16 + m] = acc[1][ct][r];
            }
        }
    }
}

__global__ void combine_kernel(const float* __restrict__ pacc, const float* __restrict__ pden,
                               float* __restrict__ out, int S) {
    size_t idx = (size_t)blockIdx.x * 256 + threadIdx.x;
    int i = (int)(idx >> 8);
    int c = (int)(idx & 255);
    int hh = c >> 7;
    float acc = 0.f, den = 0.f;
    for (int s = 0; s < S; ++s) {
        acc += pacc[(size_t)s * NN * 256 + idx];
        den += pden[((size_t)s * NN + i) * 2 + hh];
    }
    out[idx] = acc / den;
}

extern "C" void kernel_launch(void* const* d_in, const int* in_sizes, int n_in,
                              void* d_out, int out_size, void* d_ws, size_t ws_size,
                              hipStream_t stream) {
    const float* hmat = (const float*)d_in[0];
    const int*   adj  = (const int*)d_in[1];
    const float* W1   = (const float*)d_in[2];
    const float* b1   = (const float*)d_in[3];
    const float* W2   = (const float*)d_in[4];
    const float* b2   = (const float*)d_in[5];
    const float* W3   = (const float*)d_in[6];
    const float* b3   = (const float*)d_in[7];
    const float* a    = (const float*)d_in[8];
    float* out = (float*)d_out;

    char* p = (char*)d_ws;
    float* v1 = (float*)p; p += 2048;
    float* v2 = (float*)p; p += 2048;
    float* bd = (float*)p; p += 256;
    float* s1 = (float*)p; p += (size_t)NN * 2 * sizeof(float);
    float* s2 = (float*)p; p += (size_t)NN * 2 * sizeof(float);
    unsigned short* w3t = (unsigned short*)p; p += (size_t)NN * 256 * 2;
    size_t fixed = (size_t)(p - (char*)d_ws);
    size_t perS = (size_t)NN * 256 * 4 + (size_t)NN * 2 * 4;
    int S = 1;
    if      (fixed + 16 * perS <= ws_size) S = 16;
    else if (fixed + 8 * perS <= ws_size)  S = 8;
    else if (fixed + 4 * perS <= ws_size)  S = 4;
    else if (fixed + 2 * perS <= ws_size)  S = 2;
    float* pden = (float*)p; p += (size_t)S * NN * 2 * sizeof(float);
    float* pacc = (float*)p;

    prep_kernel<<<1, 512, 0, stream>>>(W1, b1, W2, b2, a, v1, v2, bd);
    s_kernel<<<NN / 4, 256, 0, stream>>>(hmat, v1, v2, bd, s1, s2);
    w3_kernel<<<NN / 64, 256, 0, stream>>>(hmat, W3, b3, w3t);
    int jc = NN / S;
    if (S == 1) {
        attn_kernel<1><<<dim3(NN / 128, 1), 256, 0, stream>>>(adj, s1, s2, w3t, nullptr, nullptr, out, jc);
    } else {
        attn_kernel<0><<<dim3(NN / 128, S), 256, 0, stream>>>(adj, s1, s2, w3t, pacc, pden, out, jc);
        combine_kernel<<<(NN * 256) / 256, 256, 0, stream>>>(pacc, pden, out, S);
    }
}

// Round 3
// 229.213 us; speedup vs baseline: 1.5644x; 1.5644x over previous
//
#include <hip/hip_runtime.h>
#include <hip/hip_bf16.h>

#define NN 8192

typedef __attribute__((ext_vector_type(8))) short short8;
typedef __attribute__((ext_vector_type(4))) float f32x4;

static __device__ __forceinline__ float bf2f(unsigned short u) {
    union { unsigned int i; float f; } v; v.i = ((unsigned int)u) << 16; return v.f;
}
static __device__ __forceinline__ unsigned short f2bf(float f) {
    union { float f; unsigned int i; } v; v.f = f;
    unsigned int lsb = (v.i >> 16) & 1u;
    v.i += 0x7fffu + lsb;
    return (unsigned short)(v.i >> 16);
}
// pack 2 floats to 2 bf16 in a u32 (HW cvt, RTNE)
static __device__ __forceinline__ unsigned int pk2(float a, float b) {
    __hip_bfloat16 ha = __float2bfloat16(a), hb = __float2bfloat16(b);
    unsigned short ua = *(unsigned short*)&ha, ub = *(unsigned short*)&hb;
    return (unsigned int)ua | ((unsigned int)ub << 16);
}

// Convert 8 contiguous f32 to bf16 hi + bf16 residual lo (for split-MFMA).
static __device__ __forceinline__ void cvt8(const float* __restrict__ p, short8& hi, short8& lo) {
    float4 u = *(const float4*)p;
    float4 v = *(const float4*)(p + 4);
    float f[8] = {u.x, u.y, u.z, u.w, v.x, v.y, v.z, v.w};
#pragma unroll
    for (int j = 0; j < 8; ++j) {
        unsigned short hb = f2bf(f[j]);
        hi[j] = (short)hb;
        lo[j] = (short)f2bf(f[j] - bf2f(hb));
    }
}

// ---- prep: v1/v2 (W^T a vectors), split over 16 blocks then reduced ----
__global__ void prep_partial(const float* __restrict__ W1, const float* __restrict__ W2,
                             const float* __restrict__ a,
                             float* __restrict__ v1p, float* __restrict__ v2p) {
    int b = blockIdx.x;            // 0..15
    int t = threadIdx.x;           // 512: (hh, k)
    int hh = t >> 8, k = t & 255;
    int c0 = (b & 7) * 16;
    const float* W = (b < 8) ? W1 : W2;
    int aoff = (b < 8) ? 0 : 128;
    float acc = 0.f;
    for (int c = c0; c < c0 + 16; ++c)
        acc += W[(size_t)(hh * 128 + c) * 256 + k] * a[hh * 256 + aoff + c];
    ((b < 8) ? v1p : v2p)[(b & 7) * 512 + t] = acc;
}

__global__ void prep_reduce(const float* __restrict__ b1, const float* __restrict__ b2,
                            const float* __restrict__ a,
                            const float* __restrict__ v1p, const float* __restrict__ v2p,
                            float* __restrict__ v1, float* __restrict__ v2, float* __restrict__ bd) {
    int t = threadIdx.x;           // 512
    float a1 = 0.f, a2 = 0.f;
    for (int b = 0; b < 8; ++b) { a1 += v1p[b * 512 + t]; a2 += v2p[b * 512 + t]; }
    v1[t] = a1;
    v2[t] = a2;
    if (t < 4) {
        int hh = t >> 1, which = t & 1;
        float d = 0.f;
        for (int c = 0; c < 128; ++c)
            d += which ? b2[hh * 128 + c] * a[hh * 256 + 128 + c]
                       : b1[hh * 128 + c] * a[hh * 256 + c];
        bd[hh * 2 + which] = d;
    }
}

// s1[n][h], s2[n][h] f32, interleaved pairs. One wave per row.
__global__ __launch_bounds__(256) void s_kernel(const float* __restrict__ hmat,
                         const float* __restrict__ v1, const float* __restrict__ v2,
                         const float* __restrict__ bd,
                         float* __restrict__ s1o, float* __restrict__ s2o) {
    int w = threadIdx.x >> 6, l = threadIdx.x & 63;
    int n = blockIdx.x * 4 + w;
    float4 hv  = *(const float4*)(hmat + (size_t)n * 256 + l * 4);
    float4 va0 = *(const float4*)(v1 + l * 4);
    float4 va1 = *(const float4*)(v1 + 256 + l * 4);
    float4 vb0 = *(const float4*)(v2 + l * 4);
    float4 vb1 = *(const float4*)(v2 + 256 + l * 4);
    float s10 = hv.x*va0.x + hv.y*va0.y + hv.z*va0.z + hv.w*va0.w;
    float s11 = hv.x*va1.x + hv.y*va1.y + hv.z*va1.z + hv.w*va1.w;
    float s20 = hv.x*vb0.x + hv.y*vb0.y + hv.z*vb0.z + hv.w*vb0.w;
    float s21 = hv.x*vb1.x + hv.y*vb1.y + hv.z*vb1.z + hv.w*vb1.w;
#pragma unroll
    for (int off = 1; off < 64; off <<= 1) {
        s10 += __shfl_xor(s10, off);
        s11 += __shfl_xor(s11, off);
        s20 += __shfl_xor(s20, off);
        s21 += __shfl_xor(s21, off);
    }
    if (l == 0) {
        s1o[n*2 + 0] = s10 + bd[0];
        s1o[n*2 + 1] = s11 + bd[2];
        s2o[n*2 + 0] = s20 + bd[1];
        s2o[n*2 + 1] = s21 + bd[3];
    }
}

// W3hT[c][n] bf16, split-bf16 3-MFMA for ~f32 accuracy.
__global__ __launch_bounds__(256) void w3_kernel(const float* __restrict__ hmat,
                                                 const float* __restrict__ W3,
                                                 const float* __restrict__ b3,
                                                 unsigned short* __restrict__ w3t) {
    int tid = threadIdx.x;
    int w = tid >> 6, l = tid & 63;
    int m = l & 15, kq = l >> 4;
    int n0 = blockIdx.x * 64 + w * 16;
    f32x4 acc[16];
#pragma unroll
    for (int ct = 0; ct < 16; ++ct) acc[ct] = (f32x4){0.f, 0.f, 0.f, 0.f};
    for (int k0 = 0; k0 < 256; k0 += 32) {
        short8 ahi, alo;
        cvt8(hmat + (size_t)(n0 + m) * 256 + k0 + kq * 8, ahi, alo);
#pragma unroll
        for (int ct = 0; ct < 16; ++ct) {
            short8 bhi, blo;
            cvt8(W3 + (size_t)(ct * 16 + m) * 256 + k0 + kq * 8, bhi, blo);
            acc[ct] = __builtin_amdgcn_mfma_f32_16x16x32_bf16(ahi, bhi, acc[ct], 0, 0, 0);
            acc[ct] = __builtin_amdgcn_mfma_f32_16x16x32_bf16(alo, bhi, acc[ct], 0, 0, 0);
            acc[ct] = __builtin_amdgcn_mfma_f32_16x16x32_bf16(ahi, blo, acc[ct], 0, 0, 0);
        }
    }
#pragma unroll
    for (int ct = 0; ct < 16; ++ct) {
        int c = ct * 16 + m;
        float bias = b3[c];
#pragma unroll
        for (int r = 0; r < 4; ++r) {
            int nn = n0 + kq * 4 + r;
            w3t[(size_t)c * NN + nn] = f2bf(acc[ct][r] + bias);
        }
    }
}

// ---- main fused attention ----
// Block: 4 waves x 32 rows = 128 rows, all 256 out cols. grid = (64, S).
// Double-buffered LDS B-tile (16 KB per j-step of 32) staged with global_load_lds,
// XOR-swizzled granules (slot = kq ^ (c&3)) applied on the GLOBAL source so the
// LDS dest stays linear (m173 pattern); ds_read_b128 is then conflict-free
// (8 lanes per 16B bank-group). adj prefetched one iteration ahead.
__global__ __launch_bounds__(256, 2) void attn_main(
        const int* __restrict__ adj, const float* __restrict__ s1a,
        const float* __restrict__ s2a, const unsigned short* __restrict__ w3t,
        unsigned short* __restrict__ pacc, float* __restrict__ pden, int jc)
{
    __shared__ uint4 btq[2][1024];   // 2 x 16 KB B-tile
    __shared__ float s2t[4096];      // s2 chunk, jc<=2048

    int tid = threadIdx.x;
    int w = tid >> 6, l = tid & 63;
    int m = l & 15, kq = l >> 4;
    int i0 = blockIdx.x * 128 + w * 32;
    int sidx = blockIdx.y;
    int j0 = sidx * jc;
    int ia = i0 + m, ib = i0 + 16 + m;
    float s1a0 = s1a[ia*2 + 0], s1a1 = s1a[ia*2 + 1];
    float s1b0 = s1a[ib*2 + 0], s1b1 = s1a[ib*2 + 1];
    const size_t rowa = (size_t)ia * NN + j0 + kq * 8;
    const size_t rowb = (size_t)ib * NN + j0 + kq * 8;

    auto stageB = [&](int bsel, int jcol) {
#pragma unroll
        for (int it = 0; it < 4; ++it) {
            int t = tid + it * 256;              // 0..1023 granules
            int c = t >> 2, g = t & 3;
            const unsigned short* src = w3t + (size_t)c * NN + jcol + ((g ^ (c & 3)) << 3);
            __builtin_amdgcn_global_load_lds(
                (const __attribute__((address_space(1))) void*)src,
                (__attribute__((address_space(3))) void*)((char*)&btq[bsel][0] + t * 16),
                16, 0, 0);
        }
    };

    f32x4 acc[2][16];
#pragma unroll
    for (int rt = 0; rt < 2; ++rt)
#pragma unroll
        for (int ct = 0; ct < 16; ++ct) acc[rt][ct] = (f32x4){0.f, 0.f, 0.f, 0.f};
    float dsa0 = 0.f, dsa1 = 0.f, dsb0 = 0.f, dsb1 = 0.f;

    // prologue: stage s2 chunk + B-tile(0) + adj(0)
    for (int x = tid; x < jc * 2; x += 256) s2t[x] = s2a[j0 * 2 + x];
    stageB(0, j0);
    int4 cA0 = *(const int4*)(adj + rowa);
    int4 cA1 = *(const int4*)(adj + rowa + 4);
    int4 cB0 = *(const int4*)(adj + rowb);
    int4 cB1 = *(const int4*)(adj + rowb + 4);
    __syncthreads();

    int buf = 0;
    for (int jt = 0; jt < jc; jt += 32) {
        bool more = (jt + 32 < jc);
        int4 nA0, nA1, nB0, nB1;
        if (more) {
            nA0 = *(const int4*)(adj + rowa + jt + 32);
            nA1 = *(const int4*)(adj + rowa + jt + 36);
            nB0 = *(const int4*)(adj + rowb + jt + 32);
            nB1 = *(const int4*)(adj + rowb + jt + 36);
            stageB(buf ^ 1, j0 + jt + 32);
        }
        int aj[8] = {cA0.x, cA0.y, cA0.z, cA0.w, cA1.x, cA1.y, cA1.z, cA1.w};
        int bj[8] = {cB0.x, cB0.y, cB0.z, cB0.w, cB1.x, cB1.y, cB1.z, cB1.w};
        union { short8 v; unsigned int u[4]; } Ua0, Ua1, Ub0, Ub1;
#pragma unroll
        for (int q = 0; q < 4; ++q) {
            float4 sv = *(const float4*)&s2t[2 * (jt + kq * 8) + 4 * q];
            float t0, t1, p0, p1;
            t0 = s1a0 + sv.x; t0 = fmaxf(t0, 0.2f * t0);
            t1 = s1a0 + sv.z; t1 = fmaxf(t1, 0.2f * t1);
            p0 = aj[2*q] ? __expf(t0) : 0.f;
            p1 = aj[2*q+1] ? __expf(t1) : 0.f;
            Ua0.u[q] = pk2(p0, p1); dsa0 += p0 + p1;
            t0 = s1a1 + sv.y; t0 = fmaxf(t0, 0.2f * t0);
            t1 = s1a1 + sv.w; t1 = fmaxf(t1, 0.2f * t1);
            p0 = aj[2*q] ? __expf(t0) : 0.f;
            p1 = aj[2*q+1] ? __expf(t1) : 0.f;
            Ua1.u[q] = pk2(p0, p1); dsa1 += p0 + p1;
            t0 = s1b0 + sv.x; t0 = fmaxf(t0, 0.2f * t0);
            t1 = s1b0 + sv.z; t1 = fmaxf(t1, 0.2f * t1);
            p0 = bj[2*q] ? __expf(t0) : 0.f;
            p1 = bj[2*q+1] ? __expf(t1) : 0.f;
            Ub0.u[q] = pk2(p0, p1); dsb0 += p0 + p1;
            t0 = s1b1 + sv.y; t0 = fmaxf(t0, 0.2f * t0);
            t1 = s1b1 + sv.w; t1 = fmaxf(t1, 0.2f * t1);
            p0 = bj[2*q] ? __expf(t0) : 0.f;
            p1 = bj[2*q+1] ? __expf(t1) : 0.f;
            Ub1.u[q] = pk2(p0, p1); dsb1 += p0 + p1;
        }
#pragma unroll
        for (int ct = 0; ct < 16; ++ct) {
            int cc = ct * 16 + m;
            short8 bfrag = *(const short8*)((const char*)&btq[buf][0] + cc * 64 + ((kq ^ (m & 3)) << 4));
            acc[0][ct] = __builtin_amdgcn_mfma_f32_16x16x32_bf16(ct < 8 ? Ua0.v : Ua1.v, bfrag, acc[0][ct], 0, 0, 0);
            acc[1][ct] = __builtin_amdgcn_mfma_f32_16x16x32_bf16(ct < 8 ? Ub0.v : Ub1.v, bfrag, acc[1][ct], 0, 0, 0);
        }
        __syncthreads();
        buf ^= 1;
        if (more) { cA0 = nA0; cA1 = nA1; cB0 = nB0; cB1 = nB1; }
    }

    dsa0 += __shfl_xor(dsa0, 16); dsa0 += __shfl_xor(dsa0, 32);
    dsa1 += __shfl_xor(dsa1, 16); dsa1 += __shfl_xor(dsa1, 32);
    dsb0 += __shfl_xor(dsb0, 16); dsb0 += __shfl_xor(dsb0, 32);
    dsb1 += __shfl_xor(dsb1, 16); dsb1 += __shfl_xor(dsb1, 32);
    if (l < 16) {
        size_t base = (size_t)sidx * NN;
        pden[(base + ia)*2 + 0] = dsa0;
        pden[(base + ia)*2 + 1] = dsa1;
        pden[(base + ib)*2 + 0] = dsb0;
        pden[(base + ib)*2 + 1] = dsb1;
    }
    size_t pb_ = (size_t)sidx * NN * 256;
#pragma unroll
    for (int r = 0; r < 4; ++r) {
        int rr = kq * 4 + r;
#pragma unroll
        for (int ct = 0; ct < 16; ++ct) {
            pacc[pb_ + (size_t)(i0 + rr)*256 + ct*16 + m]      = f2bf(acc[0][ct][r]);
            pacc[pb_ + (size_t)(i0 + 16 + rr)*256 + ct*16 + m] = f2bf(acc[1][ct][r]);
        }
    }
}

// combine: 8 outputs per thread (uint4 = 8 bf16 per partial)
__global__ void combine_kernel(const unsigned short* __restrict__ pacc, const float* __restrict__ pden,
                               float* __restrict__ out, int S) {
    size_t idx = ((size_t)blockIdx.x * 256 + threadIdx.x) * 8;
    int i = (int)(idx >> 8);
    int c = (int)(idx & 255);
    int hh = c >> 7;
    float acc[8];
#pragma unroll
    for (int e = 0; e < 8; ++e) acc[e] = 0.f;
    float den = 0.f;
    for (int s = 0; s < S; ++s) {
        uint4 v = *(const uint4*)&pacc[(size_t)s * NN * 256 + idx];
        unsigned int uu[4] = {v.x, v.y, v.z, v.w};
#pragma unroll
        for (int q = 0; q < 4; ++q) {
            acc[2*q]   += bf2f((unsigned short)(uu[q] & 0xffff));
            acc[2*q+1] += bf2f((unsigned short)(uu[q] >> 16));
        }
        den += pden[((size_t)s * NN + i) * 2 + hh];
    }
    float r = 1.f / den;
    float4 o0 = {acc[0]*r, acc[1]*r, acc[2]*r, acc[3]*r};
    float4 o1 = {acc[4]*r, acc[5]*r, acc[6]*r, acc[7]*r};
    *(float4*)&out[idx] = o0;
    *(float4*)&out[idx + 4] = o1;
}

extern "C" void kernel_launch(void* const* d_in, const int* in_sizes, int n_in,
                              void* d_out, int out_size, void* d_ws, size_t ws_size,
                              hipStream_t stream) {
    const float* hmat = (const float*)d_in[0];
    const int*   adj  = (const int*)d_in[1];
    const float* W1   = (const float*)d_in[2];
    const float* b1   = (const float*)d_in[3];
    const float* W2   = (const float*)d_in[4];
    const float* b2   = (const float*)d_in[5];
    const float* W3   = (const float*)d_in[6];
    const float* b3   = (const float*)d_in[7];
    const float* a    = (const float*)d_in[8];
    float* out = (float*)d_out;

    char* p = (char*)d_ws;
    float* v1  = (float*)p; p += 2048;
    float* v2  = (float*)p; p += 2048;
    float* bd  = (float*)p; p += 256;
    float* s1  = (float*)p; p += (size_t)NN * 2 * sizeof(float);
    float* s2  = (float*)p; p += (size_t)NN * 2 * sizeof(float);
    float* v1p = (float*)p; p += 8 * 512 * sizeof(float);
    float* v2p = (float*)p; p += 8 * 512 * sizeof(float);
    unsigned short* w3t = (unsigned short*)p; p += (size_t)NN * 256 * 2;
    size_t fixed = (size_t)(p - (char*)d_ws);
    size_t perS = (size_t)NN * 256 * 2 /*pacc bf16*/ + (size_t)NN * 2 * 4 /*pden f32*/;
    int S = 4;                               // ws known >= 38.1 MB (round-2 picked S=4 at 8.4 MB/S)
    if      (fixed + 16 * perS <= ws_size) S = 16;
    else if (fixed + 8  * perS <= ws_size) S = 8;
    float* pden = (float*)p; p += (size_t)S * NN * 2 * sizeof(float);
    unsigned short* pacc = (unsigned short*)p;

    prep_partial<<<16, 512, 0, stream>>>(W1, W2, a, v1p, v2p);
    prep_reduce<<<1, 512, 0, stream>>>(b1, b2, a, v1p, v2p, v1, v2, bd);
    s_kernel<<<NN / 4, 256, 0, stream>>>(hmat, v1, v2, bd, s1, s2);
    w3_kernel<<<NN / 64, 256, 0, stream>>>(hmat, W3, b3, w3t);
    int jc = NN / S;
    attn_main<<<dim3(NN / 128, S), 256, 0, stream>>>(adj, s1, s2, w3t, pacc, pden, jc);
    combine_kernel<<<(NN * 256) / (256 * 8), 256, 0, stream>>>(pacc, pden, out, S);
}